// Round 5
// baseline (238.301 us; speedup 1.0000x reference)
//
#include <hip/hip_runtime.h>

#define NB 4096   // batch
#define NT 512    // time steps
#define ND 32     // input features
#define NH 16     // hidden
#define CH 16     // timesteps per MFMA chunk
#define NCH (NT/CH)

typedef float f32x2 __attribute__((ext_vector_type(2)));
typedef float f32x4 __attribute__((ext_vector_type(4)));
typedef short short8 __attribute__((ext_vector_type(8)));
typedef unsigned int uint4v __attribute__((ext_vector_type(4)));

__device__ __forceinline__ unsigned cvt_pk_bf16(float lo, float hi) {
    unsigned r;
    asm("v_cvt_pk_bf16_f32 %0, %1, %2" : "=v"(r) : "v"(lo), "v"(hi));
    return r;
}
// Packed fp32 FMA: acc.x += a.x*b.x; acc.y += a.y*b.y (one VALU instr)
__device__ __forceinline__ void pk_fma(f32x2& acc, f32x2 a, f32x2 b) {
    asm("v_pk_fma_f32 %0, %1, %2, %0" : "+v"(acc) : "v"(a), "v"(b));
}
__device__ __forceinline__ float sigm(float y) {
    return __builtin_amdgcn_rcpf(1.0f + __expf(-y));
}
__device__ __forceinline__ float tanh_fast(float y) {
    return fmaf(-2.0f, __builtin_amdgcn_rcpf(1.0f + __expf(2.0f * y)), 1.0f);
}

// 8 batches per wave, two independent sets of 4 interleaved per step so each
// set's LDS h round-trip + transcendental chain hides under the other set's
// FMA work. Lane = (p = lane>>4: batch-in-set, u = lane&15: hidden unit).
// z_x = x@Wx via MFMA per 16-step chunk (R3/R4-verified fragment layouts);
// recurrence stays exact fp32.
__global__ __launch_bounds__(64, 1) void lstm8_kernel(
    const float* __restrict__ x,   // (B, T, D)
    const float* __restrict__ Wx,  // (D, 4H) cols packed [i|f|g|o]
    const float* __restrict__ Wh,  // (H, 4H)
    const float* __restrict__ bh,  // (4H)
    const float* __restrict__ Wd,  // (H, 2)
    const float* __restrict__ bd,  // (2)
    float* __restrict__ out)       // (B, 2)
{
    __shared__ float zxb[8][CH][NH][4];  // [q][step][u][i,f,g,o] = 32 KB
    __shared__ float hbuf[2][4][NH];     // [set][p][u] (2-way-per-quarter = free)

    const int lane = threadIdx.x;  // 64-thread block = 1 wave
    const int u = lane & 15;       // hidden unit (recurrence) / row,col (MFMA)
    const int p = lane >> 4;       // batch-in-set (recurrence) / K-group (MFMA)
    const int k0 = p * 8;
    const int b0 = blockIdx.x * 8;

    // MFMA B-frags: Wx cols n*16+u, k=k0..k0+7 (bf16). Verified layout (R3/R4).
    short8 bfrag[4];
    float biasn[4];
#pragma unroll
    for (int n = 0; n < 4; ++n) {
        uint4v w;
#pragma unroll
        for (int q = 0; q < 4; ++q)
            w[q] = cvt_pk_bf16(Wx[(k0 + 2 * q) * 64 + n * 16 + u],
                               Wx[(k0 + 2 * q + 1) * 64 + n * 16 + u]);
        bfrag[n] = __builtin_bit_cast(short8, w);
        biasn[n] = bh[n * 16 + u];
    }

    // Wh columns for this lane's 4 gates, packed over k-pairs (fp32 exact).
    f32x2 wh_i[8], wh_f[8], wh_g[8], wh_o[8];
#pragma unroll
    for (int j = 0; j < 8; ++j) {
        wh_i[j] = f32x2{Wh[(2 * j) * 64 + u],      Wh[(2 * j + 1) * 64 + u]};
        wh_f[j] = f32x2{Wh[(2 * j) * 64 + 16 + u], Wh[(2 * j + 1) * 64 + 16 + u]};
        wh_g[j] = f32x2{Wh[(2 * j) * 64 + 32 + u], Wh[(2 * j + 1) * 64 + 32 + u]};
        wh_o[j] = f32x2{Wh[(2 * j) * 64 + 48 + u], Wh[(2 * j + 1) * 64 + 48 + u]};
    }

    // Lane's x source: batch b0+q, row (step-in-chunk) = u, feats k0..k0+7.
    const float* xbase = x + ((size_t)b0 * NT + u) * ND + k0;

    // Prologue: load + convert chunk-0 A-frags for all 8 batches (two groups
    // of 4 to cap transient f32 register pressure).
    uint4v afr[8];
#pragma unroll
    for (int g = 0; g < 2; ++g) {
        f32x4 t0[4], t1[4];
#pragma unroll
        for (int q = 0; q < 4; ++q) {
            const float* src = xbase + (size_t)(g * 4 + q) * NT * ND;
            t0[q] = *(const f32x4*)(src);
            t1[q] = *(const f32x4*)(src + 4);
        }
#pragma unroll
        for (int q = 0; q < 4; ++q) {
            afr[g * 4 + q][0] = cvt_pk_bf16(t0[q].x, t0[q].y);
            afr[g * 4 + q][1] = cvt_pk_bf16(t0[q].z, t0[q].w);
            afr[g * 4 + q][2] = cvt_pk_bf16(t1[q].x, t1[q].y);
            afr[g * 4 + q][3] = cvt_pk_bf16(t1[q].z, t1[q].w);
        }
    }

    hbuf[0][p][u] = 0.0f;
    hbuf[1][p][u] = 0.0f;
    float c0 = 0.0f, c1 = 0.0f;

// One recurrence step for one set. SET/QOFF compile-time; CREG is c0/c1.
#define STEP(SET, QOFF, CREG)                                                 \
    {                                                                         \
        f32x4 zx = *(const f32x4*)&zxb[QOFF + p][s][u][0];                    \
        const f32x4* hv = (const f32x4*)&hbuf[SET][p][0];                     \
        f32x4 h0 = hv[0], h1 = hv[1], h2 = hv[2], h3 = hv[3];                 \
        f32x2 zi = f32x2{zx.x, 0.0f}, zf = f32x2{zx.y, 0.0f};                 \
        f32x2 zg = f32x2{zx.z, 0.0f}, zo = f32x2{zx.w, 0.0f};                 \
        f32x2 hp;                                                             \
        hp = f32x2{h0.x, h0.y};                                               \
        pk_fma(zi, hp, wh_i[0]); pk_fma(zf, hp, wh_f[0]);                     \
        pk_fma(zg, hp, wh_g[0]); pk_fma(zo, hp, wh_o[0]);                     \
        hp = f32x2{h0.z, h0.w};                                               \
        pk_fma(zi, hp, wh_i[1]); pk_fma(zf, hp, wh_f[1]);                     \
        pk_fma(zg, hp, wh_g[1]); pk_fma(zo, hp, wh_o[1]);                     \
        hp = f32x2{h1.x, h1.y};                                               \
        pk_fma(zi, hp, wh_i[2]); pk_fma(zf, hp, wh_f[2]);                     \
        pk_fma(zg, hp, wh_g[2]); pk_fma(zo, hp, wh_o[2]);                     \
        hp = f32x2{h1.z, h1.w};                                               \
        pk_fma(zi, hp, wh_i[3]); pk_fma(zf, hp, wh_f[3]);                     \
        pk_fma(zg, hp, wh_g[3]); pk_fma(zo, hp, wh_o[3]);                     \
        hp = f32x2{h2.x, h2.y};                                               \
        pk_fma(zi, hp, wh_i[4]); pk_fma(zf, hp, wh_f[4]);                     \
        pk_fma(zg, hp, wh_g[4]); pk_fma(zo, hp, wh_o[4]);                     \
        hp = f32x2{h2.z, h2.w};                                               \
        pk_fma(zi, hp, wh_i[5]); pk_fma(zf, hp, wh_f[5]);                     \
        pk_fma(zg, hp, wh_g[5]); pk_fma(zo, hp, wh_o[5]);                     \
        hp = f32x2{h3.x, h3.y};                                               \
        pk_fma(zi, hp, wh_i[6]); pk_fma(zf, hp, wh_f[6]);                     \
        pk_fma(zg, hp, wh_g[6]); pk_fma(zo, hp, wh_o[6]);                     \
        hp = f32x2{h3.z, h3.w};                                               \
        pk_fma(zi, hp, wh_i[7]); pk_fma(zf, hp, wh_f[7]);                     \
        pk_fma(zg, hp, wh_g[7]); pk_fma(zo, hp, wh_o[7]);                     \
        float ai = sigm(zi.x + zi.y);                                         \
        float afv = sigm(zf.x + zf.y);                                        \
        float ag = tanh_fast(zg.x + zg.y);                                    \
        float ao = sigm(zo.x + zo.y);                                         \
        float cn = fmaf(afv, CREG, ai * ag);                                  \
        CREG = cn;                                                            \
        hbuf[SET][p][u] = ao * tanh_fast(cn);                                 \
    }

    for (int tc = 0; tc < NCH; ++tc) {
        // MFMA staging: z_x for 8 batches x 16 steps x 64 gates.
        // C layout: col(lane&15)=u, row((lane>>4)*4+r)=step.
#pragma unroll
        for (int q = 0; q < 8; ++q) {
            short8 af = __builtin_bit_cast(short8, afr[q]);
            f32x4 acc[4];
#pragma unroll
            for (int n = 0; n < 4; ++n) {
                acc[n] = f32x4{biasn[n], biasn[n], biasn[n], biasn[n]};
                acc[n] = __builtin_amdgcn_mfma_f32_16x16x32_bf16(af, bfrag[n], acc[n], 0, 0, 0);
            }
#pragma unroll
            for (int r = 0; r < 4; ++r)
                *(f32x4*)&zxb[q][p * 4 + r][u][0] =
                    f32x4{acc[0][r], acc[1][r], acc[2][r], acc[3][r]};
        }

        const bool have_next = (tc + 1 < NCH);
        const float* xnext = xbase + (size_t)(tc + 1) * CH * ND;
        f32x4 t0[4], t1[4];  // transient f32 prefetch group

#pragma unroll
        for (int s = 0; s < CH; ++s) {
            if (s == 0 && have_next) {   // issue group A loads (batches 0-3)
#pragma unroll
                for (int q = 0; q < 4; ++q) {
                    const float* src = xnext + (size_t)q * NT * ND;
                    t0[q] = *(const f32x4*)(src);
                    t1[q] = *(const f32x4*)(src + 4);
                }
            }
            if (s == 8 && have_next) {   // convert A, issue group B loads
#pragma unroll
                for (int q = 0; q < 4; ++q) {
                    afr[q][0] = cvt_pk_bf16(t0[q].x, t0[q].y);
                    afr[q][1] = cvt_pk_bf16(t0[q].z, t0[q].w);
                    afr[q][2] = cvt_pk_bf16(t1[q].x, t1[q].y);
                    afr[q][3] = cvt_pk_bf16(t1[q].z, t1[q].w);
                }
#pragma unroll
                for (int q = 0; q < 4; ++q) {
                    const float* src = xnext + (size_t)(4 + q) * NT * ND;
                    t0[q] = *(const f32x4*)(src);
                    t1[q] = *(const f32x4*)(src + 4);
                }
            }
            if (s == 15 && have_next) {  // convert group B
#pragma unroll
                for (int q = 0; q < 4; ++q) {
                    afr[4 + q][0] = cvt_pk_bf16(t0[q].x, t0[q].y);
                    afr[4 + q][1] = cvt_pk_bf16(t0[q].z, t0[q].w);
                    afr[4 + q][2] = cvt_pk_bf16(t1[q].x, t1[q].y);
                    afr[4 + q][3] = cvt_pk_bf16(t1[q].z, t1[q].w);
                }
            }

            STEP(0, 0, c0)   // set 0: batches b0+0..3
            STEP(1, 4, c1)   // set 1: batches b0+4..7
        }
    }
#undef STEP

    // logits = c_fin @ Wd + bd (cell state!), softmax over 2; reduce over u
    // within each 16-lane group, per set.
    f32x2 wd = *(const f32x2*)&Wd[u * 2];
    float l0 = c0 * wd.x, l1 = c0 * wd.y;
    float m0 = c1 * wd.x, m1 = c1 * wd.y;
#pragma unroll
    for (int m = 1; m < 16; m <<= 1) {
        l0 += __shfl_xor(l0, m);
        l1 += __shfl_xor(l1, m);
        m0 += __shfl_xor(m0, m);
        m1 += __shfl_xor(m1, m);
    }
    if (u == 0) {
        l0 += bd[0]; l1 += bd[1];
        m0 += bd[0]; m1 += bd[1];
        *(f32x2*)&out[(b0 + p) * 2]     = f32x2{sigm(l0 - l1), sigm(l1 - l0)};
        *(f32x2*)&out[(b0 + 4 + p) * 2] = f32x2{sigm(m0 - m1), sigm(m1 - m0)};
    }
}

extern "C" void kernel_launch(void* const* d_in, const int* in_sizes, int n_in,
                              void* d_out, int out_size, void* d_ws, size_t ws_size,
                              hipStream_t stream) {
    const float* x  = (const float*)d_in[0];
    const float* Wx = (const float*)d_in[1];
    const float* Wh = (const float*)d_in[2];
    const float* bh = (const float*)d_in[3];
    const float* Wd = (const float*)d_in[4];
    const float* bd = (const float*)d_in[5];
    float* out = (float*)d_out;

    dim3 grid(NB / 8);   // 512 one-wave blocks, 8 batches each
    dim3 block(64);
    hipLaunchKernelGGL(lstm8_kernel, grid, block, 0, stream,
                       x, Wx, Wh, bh, Wd, bd, out);
}

// Round 7
// 234.224 us; speedup vs baseline: 1.0174x; 1.0174x over previous
//
#include <hip/hip_runtime.h>

#define NB 4096   // batch
#define NT 512    // time steps
#define ND 32     // input features
#define NH 16     // hidden
#define CH 16     // timesteps per MFMA chunk
#define NCH (NT/CH)

typedef float f32x2 __attribute__((ext_vector_type(2)));
typedef float f32x4 __attribute__((ext_vector_type(4)));
typedef short short8 __attribute__((ext_vector_type(8)));
typedef unsigned int uint4v __attribute__((ext_vector_type(4)));

#define LOG2E 1.4426950408889634f

__device__ __forceinline__ unsigned cvt_pk_bf16(float lo, float hi) {
    unsigned r;
    asm("v_cvt_pk_bf16_f32 %0, %1, %2" : "=v"(r) : "v"(lo), "v"(hi));
    return r;
}
__device__ __forceinline__ float sigm(float y) {
    return __builtin_amdgcn_rcpf(1.0f + __expf(-y));
}

// 4 batches per wave, 1024 waves = 1/SIMD. Lane = (p=lane>>4: batch-in-wave,
// u=lane&15: hidden unit); each lane owns gates i,f,g,o of unit u for batch
// p -> lane-local c/h update. z_x = x@Wx via MFMA per 16-step chunk
// (verified layout). h stays in a REGISTER; h@Wh via 15 pipelined shfl_xor
// with XOR-indexed pre-rotated weights; -log2e folded into weights/biases so
// activations are exp2+add+rcp; zx reads double-buffered one step ahead.
// R7 fix vs R6: cell tanh sign — t = 2*sigm(2c)-1 (R6 had 1-2*sigm(2c) = -tanh).
__global__ __launch_bounds__(256, 1) void lstm_swz_kernel(
    const float* __restrict__ x,   // (B, T, D)
    const float* __restrict__ Wx,  // (D, 4H) cols packed [i|f|g|o]
    const float* __restrict__ Wh,  // (H, 4H)
    const float* __restrict__ bh,  // (4H)
    const float* __restrict__ Wd,  // (H, 2)
    const float* __restrict__ bd,  // (2)
    float* __restrict__ out)       // (B, 2)
{
    __shared__ float zxb[4][4][CH][NH][4];  // [wave][p][step][u][i,f,g,o] = 64 KB

    const int lane = threadIdx.x & 63;
    const int wv = threadIdx.x >> 6;
    const int u = lane & 15;    // hidden unit (recurrence) / row,col (MFMA)
    const int p = lane >> 4;    // batch-in-wave (recurrence) / K-group (MFMA)
    const int k0 = p * 8;
    const int b0 = (blockIdx.x * 4 + wv) * 4;

    // MFMA B-frags: Wx cols n*16+u, k=k0..k0+7 (bf16), PRE-SCALED by
    // -log2e (gates i,f,o) or -2log2e (gate g, n==2) for exp2 activations.
    short8 bfrag[4];
    float biasn[4];
#pragma unroll
    for (int n = 0; n < 4; ++n) {
        const float sn = (n == 2) ? (-2.0f * LOG2E) : (-LOG2E);
        uint4v w;
#pragma unroll
        for (int q = 0; q < 4; ++q)
            w[q] = cvt_pk_bf16(sn * Wx[(k0 + 2 * q) * 64 + n * 16 + u],
                               sn * Wx[(k0 + 2 * q + 1) * 64 + n * 16 + u]);
        bfrag[n] = __builtin_bit_cast(short8, w);
        biasn[n] = sn * bh[n * 16 + u];
    }

    // XOR-rotated, pre-scaled Wh weights: whr_X[m] pairs with h[u^m].
    float whr_i[16], whr_f[16], whr_g[16], whr_o[16];
#pragma unroll
    for (int m = 0; m < 16; ++m) {
        const int k = (u ^ m);
        whr_i[m] = -LOG2E * Wh[k * 64 + u];
        whr_f[m] = -LOG2E * Wh[k * 64 + 16 + u];
        whr_g[m] = -2.0f * LOG2E * Wh[k * 64 + 32 + u];
        whr_o[m] = -LOG2E * Wh[k * 64 + 48 + u];
    }

    // x A-frag sources: for batch q, this lane supplies row (step) = u,
    // feats k0..k0+7. (R3/R4-verified per-lane pattern.)
    const float* xb[4];
#pragma unroll
    for (int q = 0; q < 4; ++q)
        xb[q] = x + ((size_t)(b0 + q) * NT + u) * ND + k0;

    f32x4 xa[4][2], xn[4][2];
#pragma unroll
    for (int q = 0; q < 4; ++q) {
        xa[q][0] = *(const f32x4*)(xb[q]);
        xa[q][1] = *(const f32x4*)(xb[q] + 4);
    }

    float c = 0.0f, h = 0.0f;

    for (int tc = 0; tc < NCH; ++tc) {
        const bool have_next = (tc + 1 < NCH);
        if (have_next) {
#pragma unroll
            for (int q = 0; q < 4; ++q) {
                xn[q][0] = *(const f32x4*)(xb[q] + (tc + 1) * CH * ND);
                xn[q][1] = *(const f32x4*)(xb[q] + (tc + 1) * CH * ND + 4);
            }
        }

        // z_x staging for 4 batches x 16 steps x 64 gates: 16 MFMAs, scaled
        // bias in C-init. C layout: col(lane&15)=u, row((lane>>4)*4+r)=step.
#pragma unroll
        for (int q = 0; q < 4; ++q) {
            uint4v ua;
            ua[0] = cvt_pk_bf16(xa[q][0].x, xa[q][0].y);
            ua[1] = cvt_pk_bf16(xa[q][0].z, xa[q][0].w);
            ua[2] = cvt_pk_bf16(xa[q][1].x, xa[q][1].y);
            ua[3] = cvt_pk_bf16(xa[q][1].z, xa[q][1].w);
            short8 afrag = __builtin_bit_cast(short8, ua);
            f32x4 acc[4];
#pragma unroll
            for (int n = 0; n < 4; ++n) {
                acc[n] = f32x4{biasn[n], biasn[n], biasn[n], biasn[n]};
                acc[n] = __builtin_amdgcn_mfma_f32_16x16x32_bf16(afrag, bfrag[n], acc[n], 0, 0, 0);
            }
#pragma unroll
            for (int r = 0; r < 4; ++r)
                *(f32x4*)&zxb[wv][q][p * 4 + r][u][0] =
                    f32x4{acc[0][r], acc[1][r], acc[2][r], acc[3][r]};
        }

        // Serial recurrence: zx double-buffered one step ahead; h in register,
        // broadcast via 15 independent shfl_xor (pipelined, no LDS round trip).
        f32x4 zx_cur = *(const f32x4*)&zxb[wv][p][0][u][0];
#pragma unroll
        for (int s = 0; s < CH; ++s) {
            f32x4 zx_nxt;
            if (s + 1 < CH)
                zx_nxt = *(const f32x4*)&zxb[wv][p][s + 1][u][0];

            float zi = zx_cur.x + h * whr_i[0];
            float zf = zx_cur.y + h * whr_f[0];
            float zg = zx_cur.z + h * whr_g[0];
            float zo = zx_cur.w + h * whr_o[0];
#pragma unroll
            for (int m = 1; m < 16; ++m) {
                float hm = __shfl_xor(h, m);
                zi = fmaf(hm, whr_i[m], zi);
                zf = fmaf(hm, whr_f[m], zf);
                zg = fmaf(hm, whr_g[m], zg);
                zo = fmaf(hm, whr_o[m], zo);
            }

            // z pre-scaled by -log2e (i,f,o) / -2log2e (g):
            // sigm = rcp(1+2^zs); tanh = 2*rcp(1+2^zs)-1.
            float ai = __builtin_amdgcn_rcpf(1.0f + exp2f(zi));
            float af = __builtin_amdgcn_rcpf(1.0f + exp2f(zf));
            float ag = fmaf(2.0f, __builtin_amdgcn_rcpf(1.0f + exp2f(zg)), -1.0f);
            float ao = __builtin_amdgcn_rcpf(1.0f + exp2f(zo));

            float cn = fmaf(af, c, ai * ag);   // lane-local
            c = cn;
            // tanh(cn) = 2*sigm(2cn)-1 = 2*rcp(1+2^(-2*log2e*cn)) - 1
            float t = fmaf(2.0f, __builtin_amdgcn_rcpf(
                               1.0f + exp2f((-2.0f * LOG2E) * cn)), -1.0f);
            h = ao * t;                        // stays in register
            zx_cur = zx_nxt;
        }

#pragma unroll
        for (int q = 0; q < 4; ++q) {
            if (have_next) { xa[q][0] = xn[q][0]; xa[q][1] = xn[q][1]; }
        }
    }

    // logits = c_fin @ Wd + bd (cell state!), softmax over 2; reduce over u
    // within each 16-lane group.
    f32x2 wd = *(const f32x2*)&Wd[u * 2];
    float l0 = c * wd.x;
    float l1 = c * wd.y;
#pragma unroll
    for (int m = 1; m < 16; m <<= 1) {
        l0 += __shfl_xor(l0, m);
        l1 += __shfl_xor(l1, m);
    }
    if (u == 0) {
        l0 += bd[0];
        l1 += bd[1];
        *(f32x2*)&out[(b0 + p) * 2] = f32x2{sigm(l0 - l1), sigm(l1 - l0)};
    }
}

extern "C" void kernel_launch(void* const* d_in, const int* in_sizes, int n_in,
                              void* d_out, int out_size, void* d_ws, size_t ws_size,
                              hipStream_t stream) {
    const float* x  = (const float*)d_in[0];
    const float* Wx = (const float*)d_in[1];
    const float* Wh = (const float*)d_in[2];
    const float* bh = (const float*)d_in[3];
    const float* Wd = (const float*)d_in[4];
    const float* bd = (const float*)d_in[5];
    float* out = (float*)d_out;

    dim3 grid(NB / 16);   // 4 waves/block x 4 batches/wave -> 1024 waves
    dim3 block(256);
    hipLaunchKernelGGL(lstm_swz_kernel, grid, block, 0, stream,
                       x, Wx, Wh, bh, Wd, bd, out);
}

// Round 8
// 193.645 us; speedup vs baseline: 1.2306x; 1.2096x over previous
//
#include <hip/hip_runtime.h>

#define NB 4096   // batch
#define NT 512    // time steps
#define ND 32     // input features
#define NH 16     // hidden
#define CH 16     // timesteps per MFMA chunk
#define NCH (NT/CH)

typedef float f32x2 __attribute__((ext_vector_type(2)));
typedef float f32x4 __attribute__((ext_vector_type(4)));
typedef short short8 __attribute__((ext_vector_type(8)));
typedef unsigned int uint4v __attribute__((ext_vector_type(4)));

#define LOG2E 1.4426950408889634f

__device__ __forceinline__ unsigned cvt_pk_bf16(float lo, float hi) {
    unsigned r;
    asm("v_cvt_pk_bf16_f32 %0, %1, %2" : "=v"(r) : "v"(lo), "v"(hi));
    return r;
}
__device__ __forceinline__ float sigm(float y) {
    return __builtin_amdgcn_rcpf(1.0f + __expf(-y));
}
// DPP row rotate-right by N within each 16-lane row: dst[i] = src[(i-N)&15].
// VALU pipe (v_mov_b32_dpp), no DS involvement.
template <int N>
__device__ __forceinline__ float dpp_ror(float v) {
    int s = __float_as_int(v);
    return __int_as_float(
        __builtin_amdgcn_update_dpp(s, s, 0x120 | N, 0xF, 0xF, false));
}

// 4 batches per wave, 1024 waves = 1/SIMD. Lane = (p=lane>>4: batch-in-wave,
// u=lane&15: hidden unit); each lane owns gates i,f,g,o of unit u for batch
// p -> lane-local c/h update. z_x = x@Wx via MFMA per 16-step chunk
// (verified layout). h stays in a REGISTER; h@Wh broadcast via 15 DPP row
// rotations (VALU, ~2cyc latency each -- no LDS round trip, no DS pipe) with
// rotation-indexed pre-rotated weights whr[n] <-> h[(u-n)&15]. -log2e folded
// into weights/biases so activations are exp2+add+rcp; zx reads
// double-buffered one step ahead.
__global__ __launch_bounds__(256, 1) void lstm_dpp_kernel(
    const float* __restrict__ x,   // (B, T, D)
    const float* __restrict__ Wx,  // (D, 4H) cols packed [i|f|g|o]
    const float* __restrict__ Wh,  // (H, 4H)
    const float* __restrict__ bh,  // (4H)
    const float* __restrict__ Wd,  // (H, 2)
    const float* __restrict__ bd,  // (2)
    float* __restrict__ out)       // (B, 2)
{
    __shared__ float zxb[4][4][CH][NH][4];  // [wave][p][step][u][i,f,g,o] = 64 KB

    const int lane = threadIdx.x & 63;
    const int wv = threadIdx.x >> 6;
    const int u = lane & 15;    // hidden unit (recurrence) / row,col (MFMA)
    const int p = lane >> 4;    // batch-in-wave (recurrence) / K-group (MFMA)
    const int k0 = p * 8;
    const int b0 = (blockIdx.x * 4 + wv) * 4;

    // MFMA B-frags: Wx cols n*16+u, k=k0..k0+7 (bf16), PRE-SCALED by
    // -log2e (gates i,f,o) or -2log2e (gate g, n==2) for exp2 activations.
    short8 bfrag[4];
    float biasn[4];
#pragma unroll
    for (int n = 0; n < 4; ++n) {
        const float sn = (n == 2) ? (-2.0f * LOG2E) : (-LOG2E);
        uint4v w;
#pragma unroll
        for (int q = 0; q < 4; ++q)
            w[q] = cvt_pk_bf16(sn * Wx[(k0 + 2 * q) * 64 + n * 16 + u],
                               sn * Wx[(k0 + 2 * q + 1) * 64 + n * 16 + u]);
        bfrag[n] = __builtin_bit_cast(short8, w);
        biasn[n] = sn * bh[n * 16 + u];
    }

    // Rotation-indexed, pre-scaled Wh weights: whr_X[m] pairs with h[(u-m)&15]
    // (DPP row_ror:m delivers src[(i-m)&15] to lane i).
    float whr_i[16], whr_f[16], whr_g[16], whr_o[16];
#pragma unroll
    for (int m = 0; m < 16; ++m) {
        const int k = (u - m) & 15;
        whr_i[m] = -LOG2E * Wh[k * 64 + u];
        whr_f[m] = -LOG2E * Wh[k * 64 + 16 + u];
        whr_g[m] = -2.0f * LOG2E * Wh[k * 64 + 32 + u];
        whr_o[m] = -LOG2E * Wh[k * 64 + 48 + u];
    }

    // x A-frag sources: for batch q, this lane supplies row (step) = u,
    // feats k0..k0+7. (R3/R4/R7-verified per-lane pattern.)
    const float* xb[4];
#pragma unroll
    for (int q = 0; q < 4; ++q)
        xb[q] = x + ((size_t)(b0 + q) * NT + u) * ND + k0;

    f32x4 xa[4][2], xn[4][2];
#pragma unroll
    for (int q = 0; q < 4; ++q) {
        xa[q][0] = *(const f32x4*)(xb[q]);
        xa[q][1] = *(const f32x4*)(xb[q] + 4);
    }

    float c = 0.0f, h = 0.0f;

    for (int tc = 0; tc < NCH; ++tc) {
        const bool have_next = (tc + 1 < NCH);
        if (have_next) {
#pragma unroll
            for (int q = 0; q < 4; ++q) {
                xn[q][0] = *(const f32x4*)(xb[q] + (tc + 1) * CH * ND);
                xn[q][1] = *(const f32x4*)(xb[q] + (tc + 1) * CH * ND + 4);
            }
        }

        // z_x staging for 4 batches x 16 steps x 64 gates: 16 MFMAs, scaled
        // bias in C-init. C layout: col(lane&15)=u, row((lane>>4)*4+r)=step.
#pragma unroll
        for (int q = 0; q < 4; ++q) {
            uint4v ua;
            ua[0] = cvt_pk_bf16(xa[q][0].x, xa[q][0].y);
            ua[1] = cvt_pk_bf16(xa[q][0].z, xa[q][0].w);
            ua[2] = cvt_pk_bf16(xa[q][1].x, xa[q][1].y);
            ua[3] = cvt_pk_bf16(xa[q][1].z, xa[q][1].w);
            short8 afrag = __builtin_bit_cast(short8, ua);
            f32x4 acc[4];
#pragma unroll
            for (int n = 0; n < 4; ++n) {
                acc[n] = f32x4{biasn[n], biasn[n], biasn[n], biasn[n]};
                acc[n] = __builtin_amdgcn_mfma_f32_16x16x32_bf16(afrag, bfrag[n], acc[n], 0, 0, 0);
            }
#pragma unroll
            for (int r = 0; r < 4; ++r)
                *(f32x4*)&zxb[wv][q][p * 4 + r][u][0] =
                    f32x4{acc[0][r], acc[1][r], acc[2][r], acc[3][r]};
        }

        // Serial recurrence: zx double-buffered one step ahead; h in register,
        // broadcast via DPP row rotations (VALU-only, no LDS round trip).
        f32x4 zx_cur = *(const f32x4*)&zxb[wv][p][0][u][0];
#pragma unroll
        for (int s = 0; s < CH; ++s) {
            f32x4 zx_nxt;
            if (s + 1 < CH)
                zx_nxt = *(const f32x4*)&zxb[wv][p][s + 1][u][0];

            float zi = fmaf(h, whr_i[0], zx_cur.x);
            float zf = fmaf(h, whr_f[0], zx_cur.y);
            float zg = fmaf(h, whr_g[0], zx_cur.z);
            float zo = fmaf(h, whr_o[0], zx_cur.w);
#define HTERM(M)                                                  \
            {                                                     \
                float hm = dpp_ror<M>(h);                         \
                zi = fmaf(hm, whr_i[M], zi);                      \
                zf = fmaf(hm, whr_f[M], zf);                      \
                zg = fmaf(hm, whr_g[M], zg);                      \
                zo = fmaf(hm, whr_o[M], zo);                      \
            }
            HTERM(1)  HTERM(2)  HTERM(3)  HTERM(4)
            HTERM(5)  HTERM(6)  HTERM(7)  HTERM(8)
            HTERM(9)  HTERM(10) HTERM(11) HTERM(12)
            HTERM(13) HTERM(14) HTERM(15)
#undef HTERM

            // z pre-scaled by -log2e (i,f,o) / -2log2e (g):
            // sigm = rcp(1+2^zs); tanh = 2*rcp(1+2^zs)-1.
            float ai = __builtin_amdgcn_rcpf(1.0f + exp2f(zi));
            float af = __builtin_amdgcn_rcpf(1.0f + exp2f(zf));
            float ag = fmaf(2.0f, __builtin_amdgcn_rcpf(1.0f + exp2f(zg)), -1.0f);
            float ao = __builtin_amdgcn_rcpf(1.0f + exp2f(zo));

            float cn = fmaf(af, c, ai * ag);   // lane-local
            c = cn;
            // tanh(cn) = 2*sigm(2cn)-1 = 2*rcp(1+2^(-2*log2e*cn)) - 1
            float t = fmaf(2.0f, __builtin_amdgcn_rcpf(
                               1.0f + exp2f((-2.0f * LOG2E) * cn)), -1.0f);
            h = ao * t;                        // stays in register
            zx_cur = zx_nxt;
        }

#pragma unroll
        for (int q = 0; q < 4; ++q) {
            if (have_next) { xa[q][0] = xn[q][0]; xa[q][1] = xn[q][1]; }
        }
    }

    // logits = c_fin @ Wd + bd (cell state!), softmax over 2; reduce over u
    // within each 16-lane group.
    f32x2 wd = *(const f32x2*)&Wd[u * 2];
    float l0 = c * wd.x;
    float l1 = c * wd.y;
#pragma unroll
    for (int m = 1; m < 16; m <<= 1) {
        l0 += __shfl_xor(l0, m);
        l1 += __shfl_xor(l1, m);
    }
    if (u == 0) {
        l0 += bd[0];
        l1 += bd[1];
        *(f32x2*)&out[(b0 + p) * 2] = f32x2{sigm(l0 - l1), sigm(l1 - l0)};
    }
}

extern "C" void kernel_launch(void* const* d_in, const int* in_sizes, int n_in,
                              void* d_out, int out_size, void* d_ws, size_t ws_size,
                              hipStream_t stream) {
    const float* x  = (const float*)d_in[0];
    const float* Wx = (const float*)d_in[1];
    const float* Wh = (const float*)d_in[2];
    const float* bh = (const float*)d_in[3];
    const float* Wd = (const float*)d_in[4];
    const float* bd = (const float*)d_in[5];
    float* out = (float*)d_out;

    dim3 grid(NB / 16);   // 4 waves/block x 4 batches/wave -> 1024 waves
    dim3 block(256);
    hipLaunchKernelGGL(lstm_dpp_kernel, grid, block, 0, stream,
                       x, Wx, Wh, bh, Wd, bd, out);
}

// Round 9
// 182.436 us; speedup vs baseline: 1.3062x; 1.0614x over previous
//
#include <hip/hip_runtime.h>

#define NB 4096   // batch
#define NT 512    // time steps
#define ND 32     // input features
#define NH 16     // hidden
#define CH 16     // timesteps per MFMA chunk
#define NCH (NT/CH)

typedef float f32x2 __attribute__((ext_vector_type(2)));
typedef float f32x4 __attribute__((ext_vector_type(4)));
typedef short short8 __attribute__((ext_vector_type(8)));
typedef unsigned int uint4v __attribute__((ext_vector_type(4)));

__device__ __forceinline__ unsigned cvt_pk_bf16(float lo, float hi) {
    unsigned r;
    asm("v_cvt_pk_bf16_f32 %0, %1, %2" : "=v"(r) : "v"(lo), "v"(hi));
    return r;
}
// DPP row rotate-right by N within each 16-lane row: dst[i] = src[(i-N)&15].
// VALU pipe, no DS involvement. (R8-verified with (u-N)&15 weight indexing.)
template <int N>
__device__ __forceinline__ float dpp_ror(float v) {
    int s = __float_as_int(v);
    return __int_as_float(
        __builtin_amdgcn_update_dpp(s, s, 0x120 | N, 0xF, 0xF, false));
}

// 2 batches per wave -> 2048 waves = 2 waves/SIMD so the second wave fills
// the serial chain's stalls. Lane = (p=lane>>5: batch, g=(lane>>4)&1: gate
// row, u=lane&15: hidden unit). Row g=0 owns gates (i,f) of unit u; row g=1
// owns (g,o). h@Wh via 15 DPP row rotations (register-only); the 4-gate
// combine is 2 parallel shfl_xor(.,16) pulls, then BOTH rows compute c,h
// redundantly (bitwise identical) so no h re-broadcast is needed.
// z_x = x@Wx via MFMA per 16-step chunk (R3/R4-verified layouts); sign
// scales (-1 for i,f,o; -2 for g) folded into Wx/Wh/bh so activations are
// rcp(1+__expf(z)) forms. Recurrence fp32 exact.
__global__ __launch_bounds__(256, 2) void lstm2w_kernel(
    const float* __restrict__ x,   // (B, T, D)
    const float* __restrict__ Wx,  // (D, 4H) cols packed [i|f|g|o]
    const float* __restrict__ Wh,  // (H, 4H)
    const float* __restrict__ bh,  // (4H)
    const float* __restrict__ Wd,  // (H, 2)
    const float* __restrict__ bd,  // (2)
    float* __restrict__ out)       // (B, 2)
{
    __shared__ float zxb[4][2][CH][NH][4];  // [wave][p][step][u][i,f,g,o] = 32 KB

    const int lane = threadIdx.x & 63;
    const int wv = threadIdx.x >> 6;
    const int u = lane & 15;          // hidden unit / MFMA row,col
    const int g = (lane >> 4) & 1;    // gate row: 0=(i,f), 1=(g,o)
    const int p = lane >> 5;          // batch-in-wave
    const int kgrp = lane >> 4;       // MFMA K-group (0..3)
    const int k0 = kgrp * 8;
    const int b0 = (blockIdx.x * 4 + wv) * 2;

    // MFMA B-frags: Wx cols n*16+u, k=k0..k0+7 (bf16), pre-scaled by
    // -1 (i,f,o) or -2 (gate g, n==2). Bias likewise.
    short8 bfrag[4];
    float biasn[4];
#pragma unroll
    for (int n = 0; n < 4; ++n) {
        const float sn = (n == 2) ? -2.0f : -1.0f;
        uint4v w;
#pragma unroll
        for (int q = 0; q < 4; ++q)
            w[q] = cvt_pk_bf16(sn * Wx[(k0 + 2 * q) * 64 + n * 16 + u],
                               sn * Wx[(k0 + 2 * q + 1) * 64 + n * 16 + u]);
        bfrag[n] = __builtin_bit_cast(short8, w);
        biasn[n] = sn * bh[n * 16 + u];
    }

    // Rotation-indexed pre-scaled Wh for this lane's TWO gates:
    // gate A = (g? g-gate : i), gate B = (g? o : f).
    const int gAoff = g ? 32 : 0;
    const int gBoff = g ? 48 : 16;
    const float sA = g ? -2.0f : -1.0f;
    float whrA[16], whrB[16];
#pragma unroll
    for (int m = 0; m < 16; ++m) {
        const int k = (u - m) & 15;
        whrA[m] = sA * Wh[k * 64 + gAoff + u];
        whrB[m] = -Wh[k * 64 + gBoff + u];
    }

    // Activation constants for gate A: a = sM*rcp(1+e^z)+sB (tanh when g row).
    const float sM = g ? 2.0f : 1.0f;
    const float sB = g ? -1.0f : 0.0f;

    // x A-frag sources (per batch q): lane supplies step-row u, feats k0..k0+7.
    const float* xb[2];
#pragma unroll
    for (int q = 0; q < 2; ++q)
        xb[q] = x + ((size_t)(b0 + q) * NT + u) * ND + k0;

    f32x4 xa[2][2], xn[2][2];
#pragma unroll
    for (int q = 0; q < 2; ++q) {
        xa[q][0] = *(const f32x4*)(xb[q]);
        xa[q][1] = *(const f32x4*)(xb[q] + 4);
    }

    float c = 0.0f, h = 0.0f;

    for (int tc = 0; tc < NCH; ++tc) {
        const bool have_next = (tc + 1 < NCH);
        if (have_next) {
#pragma unroll
            for (int q = 0; q < 2; ++q) {
                xn[q][0] = *(const f32x4*)(xb[q] + (tc + 1) * CH * ND);
                xn[q][1] = *(const f32x4*)(xb[q] + (tc + 1) * CH * ND + 4);
            }
        }

        // z_x staging: 2 batches x 16 steps x 64 gates = 8 MFMAs, scaled
        // bias in C-init. C layout: col(lane&15)=u, row(kgrp*4+r)=step.
#pragma unroll
        for (int q = 0; q < 2; ++q) {
            uint4v ua;
            ua[0] = cvt_pk_bf16(xa[q][0].x, xa[q][0].y);
            ua[1] = cvt_pk_bf16(xa[q][0].z, xa[q][0].w);
            ua[2] = cvt_pk_bf16(xa[q][1].x, xa[q][1].y);
            ua[3] = cvt_pk_bf16(xa[q][1].z, xa[q][1].w);
            short8 afrag = __builtin_bit_cast(short8, ua);
            f32x4 acc[4];
#pragma unroll
            for (int n = 0; n < 4; ++n) {
                acc[n] = f32x4{biasn[n], biasn[n], biasn[n], biasn[n]};
                acc[n] = __builtin_amdgcn_mfma_f32_16x16x32_bf16(afrag, bfrag[n], acc[n], 0, 0, 0);
            }
#pragma unroll
            for (int r = 0; r < 4; ++r)
                *(f32x4*)&zxb[wv][q][kgrp * 4 + r][u][0] =
                    f32x4{acc[0][r], acc[1][r], acc[2][r], acc[3][r]};
        }

        // Serial recurrence; zx (this lane's 2 gates) double-buffered one
        // step ahead; h register-resident, broadcast via DPP row rotations.
        f32x2 zx_cur = *(const f32x2*)&zxb[wv][p][0][u][2 * g];
#pragma unroll
        for (int s = 0; s < CH; ++s) {
            f32x2 zx_nxt;
            if (s + 1 < CH)
                zx_nxt = *(const f32x2*)&zxb[wv][p][s + 1][u][2 * g];

            float zA = fmaf(h, whrA[0], zx_cur.x);
            float zB = fmaf(h, whrB[0], zx_cur.y);
#define HTERM(M)                                                  \
            {                                                     \
                float hm = dpp_ror<M>(h);                         \
                zA = fmaf(hm, whrA[M], zA);                       \
                zB = fmaf(hm, whrB[M], zB);                       \
            }
            HTERM(1)  HTERM(2)  HTERM(3)  HTERM(4)
            HTERM(5)  HTERM(6)  HTERM(7)  HTERM(8)
            HTERM(9)  HTERM(10) HTERM(11) HTERM(12)
            HTERM(13) HTERM(14) HTERM(15)
#undef HTERM

            // Row g=0: aA=sigm(i), aB=sigm(f). Row g=1: aA=tanh(g), aB=sigm(o).
            float aA = fmaf(sM, __builtin_amdgcn_rcpf(1.0f + __expf(zA)), sB);
            float aB = __builtin_amdgcn_rcpf(1.0f + __expf(zB));

            // Cross-row exchange (parallel pulls); then both rows compute
            // the identical c,h update (no h re-broadcast needed).
            float oA = __shfl_xor(aA, 16);   // row0 gets tanh(g); row1 gets sigm(i)
            float oB = __shfl_xor(aB, 16);   // row0 gets sigm(o); row1 gets sigm(f)
            float ai = g ? oA : aA;
            float af = g ? oB : aB;
            float ag = g ? aA : oA;
            float ao = g ? aB : oB;

            float cn = fmaf(af, c, ai * ag);
            c = cn;
            // tanh(cn) = 2*sigm(2cn)-1
            float t = fmaf(2.0f, __builtin_amdgcn_rcpf(
                               1.0f + __expf(-2.0f * cn)), -1.0f);
            h = ao * t;
            zx_cur = zx_nxt;
        }

#pragma unroll
        for (int q = 0; q < 2; ++q) {
            if (have_next) { xa[q][0] = xn[q][0]; xa[q][1] = xn[q][1]; }
        }
    }

    // logits = c_fin @ Wd + bd (cell state!), softmax over 2. c identical on
    // both g rows; reduce over u within each 16-lane row (masks 1,2,4,8).
    f32x2 wd = *(const f32x2*)&Wd[u * 2];
    float l0 = c * wd.x;
    float l1 = c * wd.y;
#pragma unroll
    for (int m = 1; m < 16; m <<= 1) {
        l0 += __shfl_xor(l0, m);
        l1 += __shfl_xor(l1, m);
    }
    if ((lane & 31) == 0) {   // u==0, g==0 of each batch row
        l0 += bd[0];
        l1 += bd[1];
        float s0 = __builtin_amdgcn_rcpf(1.0f + __expf(l1 - l0));
        float s1 = __builtin_amdgcn_rcpf(1.0f + __expf(l0 - l1));
        *(f32x2*)&out[(b0 + p) * 2] = f32x2{s0, s1};
    }
}

extern "C" void kernel_launch(void* const* d_in, const int* in_sizes, int n_in,
                              void* d_out, int out_size, void* d_ws, size_t ws_size,
                              hipStream_t stream) {
    const float* x  = (const float*)d_in[0];
    const float* Wx = (const float*)d_in[1];
    const float* Wh = (const float*)d_in[2];
    const float* bh = (const float*)d_in[3];
    const float* Wd = (const float*)d_in[4];
    const float* bd = (const float*)d_in[5];
    float* out = (float*)d_out;

    dim3 grid(NB / 8);    // 512 blocks x 4 waves x 2 batches = 4096
    dim3 block(256);
    hipLaunchKernelGGL(lstm2w_kernel, grid, block, 0, stream,
                       x, Wx, Wh, bh, Wd, bd, out);
}

// Round 11
// 152.740 us; speedup vs baseline: 1.5602x; 1.1944x over previous
//
#include <hip/hip_runtime.h>

#define NB 4096   // batch
#define NT 512    // time steps
#define ND 32     // input features
#define NH 16     // hidden
#define CH 16     // timesteps per MFMA chunk
#define NCH (NT/CH)
#define LOG2E 1.4426950408889634f

typedef float f32x2 __attribute__((ext_vector_type(2)));
typedef float f32x4 __attribute__((ext_vector_type(4)));
typedef short short8 __attribute__((ext_vector_type(8)));
typedef unsigned int uint4v __attribute__((ext_vector_type(4)));

__device__ __forceinline__ unsigned cvt_pk_bf16(float lo, float hi) {
    unsigned r;
    asm("v_cvt_pk_bf16_f32 %0, %1, %2" : "=v"(r) : "v"(lo), "v"(hi));
    return r;
}
// Guaranteed single v_exp_f32 (exp2). libm exp2f (non-fast-math) emits a
// guarded multi-instruction sequence (R7/R8 regression source).
__device__ __forceinline__ float exp2_fast(float x) {
    float r;
    asm("v_exp_f32 %0, %1" : "=v"(r) : "v"(x));
    return r;
}
// DPP row rotate-right by N within each 16-lane row: dst[i] = src[(i-N)&15].
// (R8-verified with (u-N)&15 weight indexing.)
template <int N>
__device__ __forceinline__ float dpp_ror(float v) {
    int s = __float_as_int(v);
    return __int_as_float(
        __builtin_amdgcn_update_dpp(s, s, 0x120 | N, 0xF, 0xF, false));
}
// Packed fp32 FMA (VOP3P: all operands are 64-bit pairs; R2/R4-verified).
__device__ __forceinline__ void pk_fma(f32x2& acc, f32x2 a, f32x2 b) {
    asm("v_pk_fma_f32 %0, %1, %2, %0" : "+v"(acc) : "v"(a), "v"(b));
}

// 4 batches per wave, 1024 waves = 1/SIMD. Lane = (p=lane>>4, u=lane&15);
// each lane owns gates i,f,g,o of unit u for batch p (lane-local c/h).
// z_x = x@Wx via MFMA per 16-step chunk (verified layout), staged through
// LDS once, then PRELOADED to registers in 8-step halves so the serial loop
// is DS-free. h@Wh via 15 DPP rotations, each dup'd to a {hm,hm} pair
// (1 mov) feeding 2 v_pk_fma_f32. -log2e / -2log2e folded into Wx/Wh/bh
// (R7-verified) so every activation is rcp(1+v_exp(z)).
__global__ __launch_bounds__(256, 1) void lstm_r11_kernel(
    const float* __restrict__ x,   // (B, T, D)
    const float* __restrict__ Wx,  // (D, 4H) cols packed [i|f|g|o]
    const float* __restrict__ Wh,  // (H, 4H)
    const float* __restrict__ bh,  // (4H)
    const float* __restrict__ Wd,  // (H, 2)
    const float* __restrict__ bd,  // (2)
    float* __restrict__ out)       // (B, 2)
{
    __shared__ float zxb[4][4][CH][NH][4];  // [wave][p][step][u][i,f,g,o] = 64 KB

    const int lane = threadIdx.x & 63;
    const int wv = threadIdx.x >> 6;
    const int u = lane & 15;    // hidden unit / MFMA row,col
    const int p = lane >> 4;    // batch-in-wave / MFMA K-group
    const int k0 = p * 8;
    const int b0 = (blockIdx.x * 4 + wv) * 4;

    // MFMA B-frags: Wx cols n*16+u, k=k0..k0+7 (bf16), pre-scaled by
    // -log2e (i,f,o) or -2log2e (g, n==2). Bias likewise.
    short8 bfrag[4];
    float biasn[4];
#pragma unroll
    for (int n = 0; n < 4; ++n) {
        const float sn = (n == 2) ? (-2.0f * LOG2E) : (-LOG2E);
        uint4v w;
#pragma unroll
        for (int q = 0; q < 4; ++q)
            w[q] = cvt_pk_bf16(sn * Wx[(k0 + 2 * q) * 64 + n * 16 + u],
                               sn * Wx[(k0 + 2 * q + 1) * 64 + n * 16 + u]);
        bfrag[n] = __builtin_bit_cast(short8, w);
        biasn[n] = sn * bh[n * 16 + u];
    }

    // Rotation-indexed pre-scaled Wh pairs: whif[m]={i,f}, whgo[m]={g,o},
    // paired with h[(u-m)&15] from dpp_ror<m>.
    f32x2 whif[16], whgo[16];
#pragma unroll
    for (int m = 0; m < 16; ++m) {
        const int k = (u - m) & 15;
        whif[m] = f32x2{-LOG2E * Wh[k * 64 + u],
                        -LOG2E * Wh[k * 64 + 16 + u]};
        whgo[m] = f32x2{-2.0f * LOG2E * Wh[k * 64 + 32 + u],
                        -LOG2E * Wh[k * 64 + 48 + u]};
    }

    // x A-frag sources (R3/R4/R8-verified per-lane pattern).
    const float* xb[4];
#pragma unroll
    for (int q = 0; q < 4; ++q)
        xb[q] = x + ((size_t)(b0 + q) * NT + u) * ND + k0;

    f32x4 xa[4][2], xn[4][2];
#pragma unroll
    for (int q = 0; q < 4; ++q) {
        xa[q][0] = *(const f32x4*)(xb[q]);
        xa[q][1] = *(const f32x4*)(xb[q] + 4);
    }

    float c = 0.0f, h = 0.0f;

    for (int tc = 0; tc < NCH; ++tc) {
        const bool have_next = (tc + 1 < NCH);
        if (have_next) {
#pragma unroll
            for (int q = 0; q < 4; ++q) {
                xn[q][0] = *(const f32x4*)(xb[q] + (tc + 1) * CH * ND);
                xn[q][1] = *(const f32x4*)(xb[q] + (tc + 1) * CH * ND + 4);
            }
        }

        // z_x staging: 4 batches x 16 steps x 64 gates = 16 MFMAs, scaled
        // bias in C-init. C layout: col(lane&15)=u, row((lane>>4)*4+r)=step.
#pragma unroll
        for (int q = 0; q < 4; ++q) {
            uint4v ua;
            ua[0] = cvt_pk_bf16(xa[q][0].x, xa[q][0].y);
            ua[1] = cvt_pk_bf16(xa[q][0].z, xa[q][0].w);
            ua[2] = cvt_pk_bf16(xa[q][1].x, xa[q][1].y);
            ua[3] = cvt_pk_bf16(xa[q][1].z, xa[q][1].w);
            short8 afrag = __builtin_bit_cast(short8, ua);
            f32x4 acc[4];
#pragma unroll
            for (int n = 0; n < 4; ++n) {
                acc[n] = f32x4{biasn[n], biasn[n], biasn[n], biasn[n]};
                acc[n] = __builtin_amdgcn_mfma_f32_16x16x32_bf16(afrag, bfrag[n], acc[n], 0, 0, 0);
            }
#pragma unroll
            for (int r = 0; r < 4; ++r)
                *(f32x4*)&zxb[wv][q][p * 4 + r][u][0] =
                    f32x4{acc[0][r], acc[1][r], acc[2][r], acc[3][r]};
        }

        // Serial recurrence in 8-step halves: preload zx to registers, then
        // a DS-free, pure-VALU step body.
#pragma unroll
        for (int half = 0; half < 2; ++half) {
            f32x2 zr[8][2];
#pragma unroll
            for (int s = 0; s < 8; ++s) {
                f32x4 v = *(const f32x4*)&zxb[wv][p][half * 8 + s][u][0];
                zr[s][0] = f32x2{v.x, v.y};
                zr[s][1] = f32x2{v.z, v.w};
            }
#pragma unroll
            for (int s = 0; s < 8; ++s) {
                f32x2 zif = zr[s][0];   // {zi, zf} (scaled)
                f32x2 zgo = zr[s][1];   // {zg, zo} (scaled)
                f32x2 h2 = f32x2{h, h};
                pk_fma(zif, h2, whif[0]);
                pk_fma(zgo, h2, whgo[0]);
#define HTERM(M)                                                  \
                {                                                 \
                    float hm = dpp_ror<M>(h);                     \
                    f32x2 hm2 = f32x2{hm, hm};                    \
                    pk_fma(zif, hm2, whif[M]);                    \
                    pk_fma(zgo, hm2, whgo[M]);                    \
                }
                HTERM(1)  HTERM(2)  HTERM(3)  HTERM(4)
                HTERM(5)  HTERM(6)  HTERM(7)  HTERM(8)
                HTERM(9)  HTERM(10) HTERM(11) HTERM(12)
                HTERM(13) HTERM(14) HTERM(15)
#undef HTERM
                // sigm = rcp(1+2^zs); tanh = 2*rcp(1+2^zs)-1 (zs pre-scaled).
                float ai = __builtin_amdgcn_rcpf(1.0f + exp2_fast(zif.x));
                float af = __builtin_amdgcn_rcpf(1.0f + exp2_fast(zif.y));
                float ag = fmaf(2.0f, __builtin_amdgcn_rcpf(1.0f + exp2_fast(zgo.x)), -1.0f);
                float ao = __builtin_amdgcn_rcpf(1.0f + exp2_fast(zgo.y));

                float cn = fmaf(af, c, ai * ag);   // lane-local
                c = cn;
                // tanh(cn) = 2*rcp(1+2^(-2*log2e*cn)) - 1
                float t = fmaf(2.0f, __builtin_amdgcn_rcpf(
                                   1.0f + exp2_fast((-2.0f * LOG2E) * cn)), -1.0f);
                h = ao * t;
            }
        }

#pragma unroll
        for (int q = 0; q < 4; ++q) {
            if (have_next) { xa[q][0] = xn[q][0]; xa[q][1] = xn[q][1]; }
        }
    }

    // logits = c_fin @ Wd + bd (cell state!), softmax over 2; reduce over u
    // within each 16-lane group.
    f32x2 wd = *(const f32x2*)&Wd[u * 2];
    float l0 = c * wd.x;
    float l1 = c * wd.y;
#pragma unroll
    for (int m = 1; m < 16; m <<= 1) {
        l0 += __shfl_xor(l0, m);
        l1 += __shfl_xor(l1, m);
    }
    if (u == 0) {
        l0 += bd[0];
        l1 += bd[1];
        float s0 = __builtin_amdgcn_rcpf(1.0f + exp2_fast(LOG2E * (l1 - l0)));
        float s1 = __builtin_amdgcn_rcpf(1.0f + exp2_fast(LOG2E * (l0 - l1)));
        *(f32x2*)&out[(b0 + p) * 2] = f32x2{s0, s1};
    }
}

extern "C" void kernel_launch(void* const* d_in, const int* in_sizes, int n_in,
                              void* d_out, int out_size, void* d_ws, size_t ws_size,
                              hipStream_t stream) {
    const float* x  = (const float*)d_in[0];
    const float* Wx = (const float*)d_in[1];
    const float* Wh = (const float*)d_in[2];
    const float* bh = (const float*)d_in[3];
    const float* Wd = (const float*)d_in[4];
    const float* bd = (const float*)d_in[5];
    float* out = (float*)d_out;

    dim3 grid(NB / 16);   // 4 waves/block x 4 batches/wave -> 1024 waves
    dim3 block(256);
    hipLaunchKernelGGL(lstm_r11_kernel, grid, block, 0, stream,
                       x, Wx, Wh, bh, Wd, bd, out);
}

// Round 12
// 136.078 us; speedup vs baseline: 1.7512x; 1.1224x over previous
//
#include <hip/hip_runtime.h>

#define NB 4096   // batch
#define NT 512    // time steps
#define ND 32     // input features
#define NH 16     // hidden
#define CH 16     // timesteps per MFMA chunk
#define NCH (NT/CH)
#define LOG2E 1.4426950408889634f

typedef float f32x2 __attribute__((ext_vector_type(2)));
typedef float f32x4 __attribute__((ext_vector_type(4)));
typedef short short8 __attribute__((ext_vector_type(8)));
typedef unsigned int uint4v __attribute__((ext_vector_type(4)));

__device__ __forceinline__ unsigned cvt_pk_bf16(float lo, float hi) {
    unsigned r;
    asm("v_cvt_pk_bf16_f32 %0, %1, %2" : "=v"(r) : "v"(lo), "v"(hi));
    return r;
}
// Guaranteed single v_exp_f32 (exp2); libm exp2f emits a guarded sequence.
__device__ __forceinline__ float exp2_fast(float x) {
    float r;
    asm("v_exp_f32 %0, %1" : "=v"(r) : "v"(x));
    return r;
}
// DPP row rotate-right by N within each 16-lane row: dst[i] = src[(i-N)&15].
// (R8/R11-verified with (u-N)&15 weight indexing.)
template <int N>
__device__ __forceinline__ float dpp_ror(float v) {
    int s = __float_as_int(v);
    return __int_as_float(
        __builtin_amdgcn_update_dpp(s, s, 0x120 | N, 0xF, 0xF, false));
}
// Packed fp32 ops (VOP3P, all operands 64-bit pairs; R11-verified).
__device__ __forceinline__ void pk_fma(f32x2& acc, f32x2 a, f32x2 b) {
    asm("v_pk_fma_f32 %0, %1, %2, %0" : "+v"(acc) : "v"(a), "v"(b));
}
__device__ __forceinline__ void pk_mul(f32x2& d, f32x2 a, f32x2 b) {
    asm("v_pk_mul_f32 %0, %1, %2" : "=v"(d) : "v"(a), "v"(b));
}

// 4 batches per wave, 1024 waves = 1/SIMD. Lane = (p=lane>>4, u=lane&15);
// lane owns gates i,f,g,o of unit u for batch p (lane-local c/h update).
// vs R11: (1) m-pair DPP — hp_j = {ror<2j>(h), ror<2j+1>(h)} pairs feed one
// pk_fma per gate with pre-paired weights (no {hm,hm} dup movs); (2) MFMA
// staging for chunk t+1 is SPREAD through chunk t's step loop (double-
// buffered zxb, 128 KB LDS) so MFMA/DS-pipe work fills VALU stall cycles.
// -log2e/-2log2e folded into Wx/Wh/bh; activations are rcp(1+v_exp(z)).
__global__ __launch_bounds__(256, 1) void lstm_r12_kernel(
    const float* __restrict__ x,   // (B, T, D)
    const float* __restrict__ Wx,  // (D, 4H) cols packed [i|f|g|o]
    const float* __restrict__ Wh,  // (H, 4H)
    const float* __restrict__ bh,  // (4H)
    const float* __restrict__ Wd,  // (H, 2)
    const float* __restrict__ bd,  // (2)
    float* __restrict__ out)       // (B, 2)
{
    __shared__ float zxb[2][4][4][CH][NH][4];  // [dbuf][wave][p][step][u][ifgo] = 128 KB

    const int lane = threadIdx.x & 63;
    const int wv = threadIdx.x >> 6;
    const int u = lane & 15;    // hidden unit / MFMA row,col
    const int p = lane >> 4;    // batch-in-wave / MFMA K-group
    const int k0 = p * 8;
    const int b0 = (blockIdx.x * 4 + wv) * 4;

    // MFMA B-frags: Wx cols n*16+u, k=k0..k0+7 (bf16), pre-scaled by
    // -log2e (i,f,o) or -2log2e (g, n==2). Bias likewise.
    short8 bfrag[4];
    float biasn[4];
#pragma unroll
    for (int n = 0; n < 4; ++n) {
        const float sn = (n == 2) ? (-2.0f * LOG2E) : (-LOG2E);
        uint4v w;
#pragma unroll
        for (int q = 0; q < 4; ++q)
            w[q] = cvt_pk_bf16(sn * Wx[(k0 + 2 * q) * 64 + n * 16 + u],
                               sn * Wx[(k0 + 2 * q + 1) * 64 + n * 16 + u]);
        bfrag[n] = __builtin_bit_cast(short8, w);
        biasn[n] = sn * bh[n * 16 + u];
    }

    // m-paired, rotation-indexed, pre-scaled Wh: wpX[j] = {wX[(u-2j)&15],
    // wX[(u-2j-1)&15]} pairs with hp_j = {ror<2j>(h), ror<2j+1>(h)}.
    f32x2 wpi[8], wpf[8], wpg[8], wpo[8];
#pragma unroll
    for (int j = 0; j < 8; ++j) {
        const int ke = (u - 2 * j) & 15;
        const int ko = (u - 2 * j - 1) & 15;
        wpi[j] = f32x2{-LOG2E * Wh[ke * 64 + u],      -LOG2E * Wh[ko * 64 + u]};
        wpf[j] = f32x2{-LOG2E * Wh[ke * 64 + 16 + u], -LOG2E * Wh[ko * 64 + 16 + u]};
        wpg[j] = f32x2{-2.0f * LOG2E * Wh[ke * 64 + 32 + u],
                       -2.0f * LOG2E * Wh[ko * 64 + 32 + u]};
        wpo[j] = f32x2{-LOG2E * Wh[ke * 64 + 48 + u], -LOG2E * Wh[ko * 64 + 48 + u]};
    }

    // x A-frag sources (R3/R4/R11-verified per-lane pattern).
    const float* xb[4];
#pragma unroll
    for (int q = 0; q < 4; ++q)
        xb[q] = x + ((size_t)(b0 + q) * NT + u) * ND + k0;

    // Prologue: bulk-stage chunk 0 into zxb[0].
    {
        f32x4 t0[4], t1[4];
#pragma unroll
        for (int q = 0; q < 4; ++q) {
            t0[q] = *(const f32x4*)(xb[q]);
            t1[q] = *(const f32x4*)(xb[q] + 4);
        }
#pragma unroll
        for (int q = 0; q < 4; ++q) {
            uint4v ua;
            ua[0] = cvt_pk_bf16(t0[q].x, t0[q].y);
            ua[1] = cvt_pk_bf16(t0[q].z, t0[q].w);
            ua[2] = cvt_pk_bf16(t1[q].x, t1[q].y);
            ua[3] = cvt_pk_bf16(t1[q].z, t1[q].w);
            short8 afrag = __builtin_bit_cast(short8, ua);
            f32x4 acc[4];
#pragma unroll
            for (int n = 0; n < 4; ++n) {
                acc[n] = f32x4{biasn[n], biasn[n], biasn[n], biasn[n]};
                acc[n] = __builtin_amdgcn_mfma_f32_16x16x32_bf16(afrag, bfrag[n], acc[n], 0, 0, 0);
            }
#pragma unroll
            for (int r = 0; r < 4; ++r)
                *(f32x4*)&zxb[0][wv][q][p * 4 + r][u][0] =
                    f32x4{acc[0][r], acc[1][r], acc[2][r], acc[3][r]};
        }
    }

    float c = 0.0f, h = 0.0f;
    f32x4 xn0[4], xn1[4];   // next-chunk x prefetch (loaded ss==0, used ss>=8)
    f32x4 accq[4];          // next-chunk MFMA results (even ss -> odd ss)

    for (int tc = 0; tc < NCH; ++tc) {
        const int cur = tc & 1, nxt = cur ^ 1;
        const bool have_next = (tc + 1 < NCH);

#pragma unroll
        for (int half = 0; half < 2; ++half) {
            // Preload this half's zx rows to registers (DS-free step body).
            f32x4 zr[8];
#pragma unroll
            for (int s = 0; s < 8; ++s)
                zr[s] = *(const f32x4*)&zxb[cur][wv][p][half * 8 + s][u][0];

#pragma unroll
            for (int s = 0; s < 8; ++s) {
                const int ss = half * 8 + s;   // compile-time after unroll

                // --- interleaved staging for chunk tc+1 (fills VALU stalls) ---
                if (ss == 0 && have_next) {
#pragma unroll
                    for (int q = 0; q < 4; ++q) {
                        xn0[q] = *(const f32x4*)(xb[q] + (tc + 1) * CH * ND);
                        xn1[q] = *(const f32x4*)(xb[q] + (tc + 1) * CH * ND + 4);
                    }
                }
                if (ss >= 8 && (ss & 1) == 0 && have_next) {
                    const int q = (ss - 8) >> 1;
                    uint4v ua;
                    ua[0] = cvt_pk_bf16(xn0[q].x, xn0[q].y);
                    ua[1] = cvt_pk_bf16(xn0[q].z, xn0[q].w);
                    ua[2] = cvt_pk_bf16(xn1[q].x, xn1[q].y);
                    ua[3] = cvt_pk_bf16(xn1[q].z, xn1[q].w);
                    short8 afrag = __builtin_bit_cast(short8, ua);
#pragma unroll
                    for (int n = 0; n < 4; ++n) {
                        accq[n] = f32x4{biasn[n], biasn[n], biasn[n], biasn[n]};
                        accq[n] = __builtin_amdgcn_mfma_f32_16x16x32_bf16(afrag, bfrag[n], accq[n], 0, 0, 0);
                    }
                }
                if (ss >= 9 && (ss & 1) == 1 && have_next) {
                    const int q = (ss - 9) >> 1;
#pragma unroll
                    for (int r = 0; r < 4; ++r)
                        *(f32x4*)&zxb[nxt][wv][q][p * 4 + r][u][0] =
                            f32x4{accq[0][r], accq[1][r], accq[2][r], accq[3][r]};
                }

                // --- recurrence step (pure VALU) ---
                f32x4 zx = zr[s];
                f32x2 z_i, z_f, z_g, z_o;
                float r1 = dpp_ror<1>(h);
                f32x2 hp0 = f32x2{h, r1};
                pk_mul(z_i, hp0, wpi[0]);
                pk_mul(z_f, hp0, wpf[0]);
                pk_mul(z_g, hp0, wpg[0]);
                pk_mul(z_o, hp0, wpo[0]);
#define JTERM(J)                                                     \
                {                                                    \
                    f32x2 hp = f32x2{dpp_ror<2*J>(h),                \
                                     dpp_ror<2*J+1>(h)};             \
                    pk_fma(z_i, hp, wpi[J]);                         \
                    pk_fma(z_f, hp, wpf[J]);                         \
                    pk_fma(z_g, hp, wpg[J]);                         \
                    pk_fma(z_o, hp, wpo[J]);                         \
                }
                JTERM(1) JTERM(2) JTERM(3) JTERM(4)
                JTERM(5) JTERM(6) JTERM(7)
#undef JTERM
                float zi = (z_i.x + z_i.y) + zx.x;
                float zf = (z_f.x + z_f.y) + zx.y;
                float zg = (z_g.x + z_g.y) + zx.z;
                float zo = (z_o.x + z_o.y) + zx.w;

                // z pre-scaled by -log2e (i,f,o) / -2log2e (g):
                // sigm = rcp(1+2^zs); tanh = 2*rcp(1+2^zs)-1.
                float ai = __builtin_amdgcn_rcpf(1.0f + exp2_fast(zi));
                float af = __builtin_amdgcn_rcpf(1.0f + exp2_fast(zf));
                float ag = fmaf(2.0f, __builtin_amdgcn_rcpf(1.0f + exp2_fast(zg)), -1.0f);
                float ao = __builtin_amdgcn_rcpf(1.0f + exp2_fast(zo));

                float cn = fmaf(af, c, ai * ag);   // lane-local
                c = cn;
                // tanh(cn) = 2*rcp(1+2^(-2*log2e*cn)) - 1
                float t = fmaf(2.0f, __builtin_amdgcn_rcpf(
                                   1.0f + exp2_fast((-2.0f * LOG2E) * cn)), -1.0f);
                h = ao * t;
            }
        }
    }

    // logits = c_fin @ Wd + bd (cell state!), softmax over 2; reduce over u
    // within each 16-lane group.
    f32x2 wd = *(const f32x2*)&Wd[u * 2];
    float l0 = c * wd.x;
    float l1 = c * wd.y;
#pragma unroll
    for (int m = 1; m < 16; m <<= 1) {
        l0 += __shfl_xor(l0, m);
        l1 += __shfl_xor(l1, m);
    }
    if (u == 0) {
        l0 += bd[0];
        l1 += bd[1];
        float s0 = __builtin_amdgcn_rcpf(1.0f + exp2_fast(LOG2E * (l1 - l0)));
        float s1 = __builtin_amdgcn_rcpf(1.0f + exp2_fast(LOG2E * (l0 - l1)));
        *(f32x2*)&out[(b0 + p) * 2] = f32x2{s0, s1};
    }
}

extern "C" void kernel_launch(void* const* d_in, const int* in_sizes, int n_in,
                              void* d_out, int out_size, void* d_ws, size_t ws_size,
                              hipStream_t stream) {
    const float* x  = (const float*)d_in[0];
    const float* Wx = (const float*)d_in[1];
    const float* Wh = (const float*)d_in[2];
    const float* bh = (const float*)d_in[3];
    const float* Wd = (const float*)d_in[4];
    const float* bd = (const float*)d_in[5];
    float* out = (float*)d_out;

    dim3 grid(NB / 16);   // 4 waves/block x 4 batches/wave -> 1024 waves
    dim3 block(256);
    hipLaunchKernelGGL(lstm_r12_kernel, grid, block, 0, stream,
                       x, Wx, Wh, bh, Wd, bd, out);
}